// Round 1
// 171.672 us; speedup vs baseline: 1.2247x; 1.2247x over previous
//
#include <hip/hip_runtime.h>

// Problem: N_FEAT=12, BATCH=64.
// Identity (verified in prior session): left = min(fl·W, fu·W), right = fu·W
// where W = Moebius transform (over the 12-bit subset lattice) of
// FM = min(fm, 1), fm the popcount-level DP over |ie_vars|. fmat is a
// deterministic 0/1 subset/parity indicator matrix, folded analytically.
//
// This version fuses build-W + batch into ONE kernel: 64 blocks (one per
// batch row), each block rebuilds W redundantly in its own LDS. Redundant
// across CUs but parallel; removes one launch + global W round-trip, and
// the DP is restructured:
//  - ie_vars staged to LDS (coalesced) so the serial DP chain never
//    touches global memory.
//  - per-popcount-level compact work lists built via colex combinatorial
//    rank (no atomics): each level is ONE branchless body per thread.
//  - Moebius passes for bits 0..7 are wave-chunk-local (lockstep wave64,
//    in-order LDS) -> no barrier; only bits 8..11 need __syncthreads.

#define NB 12
#define NMASK 4096  // 2^12

// C(b, i) for b in 0..11 (rows), i in 0..12 (cols); zero when i > b.
__constant__ int d_BIN[156] = {
    1, 0,  0,  0,   0,   0,   0,   0,   0,  0,  0, 0, 0,   // b=0
    1, 1,  0,  0,   0,   0,   0,   0,   0,  0,  0, 0, 0,   // b=1
    1, 2,  1,  0,   0,   0,   0,   0,   0,  0,  0, 0, 0,   // b=2
    1, 3,  3,  1,   0,   0,   0,   0,   0,  0,  0, 0, 0,   // b=3
    1, 4,  6,  4,   1,   0,   0,   0,   0,  0,  0, 0, 0,   // b=4
    1, 5, 10, 10,   5,   1,   0,   0,   0,  0,  0, 0, 0,   // b=5
    1, 6, 15, 20,  15,   6,   1,   0,   0,  0,  0, 0, 0,   // b=6
    1, 7, 21, 35,  35,  21,   7,   1,   0,  0,  0, 0, 0,   // b=7
    1, 8, 28, 56,  70,  56,  28,   8,   1,  0,  0, 0, 0,   // b=8
    1, 9, 36, 84, 126, 126,  84,  36,   9,  1,  0, 0, 0,   // b=9
    1, 10, 45, 120, 210, 252, 210, 120, 45, 10, 1, 0, 0,   // b=10
    1, 11, 55, 165, 330, 462, 462, 330, 165, 55, 11, 1, 0  // b=11
};

// Level start offsets: OFF[l] = sum_{j=1..l-1} C(12, j)  (mask 0 excluded).
__constant__ int d_OFF[13] = {0, 0, 12, 78, 298, 793, 1585,
                              2509, 3301, 3796, 4016, 4082, 4094};

__global__ __launch_bounds__(1024) void k_fused(
    const float* __restrict__ x, const float* __restrict__ ie,
    float* __restrict__ out) {
  __shared__ float g[NMASK];            // fm -> FM -> W (in place)
  __shared__ float v[NMASK];            // |ie_vars| staged, v[m] = |ie[m-1]|
  __shared__ unsigned short idx[NMASK]; // per-level compact mask lists
  __shared__ float xs[24];              // row of x: [0..11]=datal [12..23]=datau
  __shared__ int sBIN[156];
  __shared__ int sOFF[13];
  __shared__ float rA[16], rB[16];

  const int tid = threadIdx.x;
  const int lane = tid & 63;
  const int wave = tid >> 6;
  const int cbase = wave << 8;  // this wave's exclusive 256-mask chunk

  // ---- stage constants + inputs into LDS (coalesced) ----
  if (tid < 156) sBIN[tid] = d_BIN[tid];
  if (tid < 13) sOFF[tid] = d_OFF[tid];
  if (tid < 24) xs[tid] = x[blockIdx.x * 24 + tid];
  for (int i = tid; i < NMASK - 2; i += 1024) v[i + 1] = fabsf(ie[i]);
  __syncthreads();

  // ---- build compact per-popcount-level lists via colex rank ----
  // rank of {b1<...<bl} among popcount-l masks = sum_i C(b_i, i); bijective.
  for (int m = tid; m < NMASK; m += 1024) {
    if (m == 0) {
      g[0] = 0.0f;  // absorbs the single-bit-mask edge case in Phase A
      continue;
    }
    int pc = 0, r = 0;
#pragma unroll
    for (int b = 0; b < NB; ++b)
      if (m & (1 << b)) { ++pc; r += sBIN[b * 13 + pc]; }
    idx[sOFF[pc] + r] = (unsigned short)m;
  }
  __syncthreads();

  // ---- Phase A: popcount-level DP, fm[m] = v[m] + max_{b in m} fm[m^b] ----
  // Levels 1..11 cover masks 1..4094 (level 12 = {4095} excluded, as in ref).
  // Each level fits in one block-sweep (max C(12,6)=924 <= 1024 threads).
  constexpr int OFF_A[13] = {0, 0, 12, 78, 298, 793, 1585,
                             2509, 3301, 3796, 4016, 4082, 4094};
#pragma unroll
  for (int lv = 1; lv <= 11; ++lv) {
    const int u = OFF_A[lv] + tid;
    if (u < OFF_A[lv + 1]) {
      const int m = (int)idx[u];
      float best = 0.0f;
#pragma unroll
      for (int b = 0; b < NB; ++b) {
        // branchless: unset bits read g[0] == 0 (identity for max; fm >= 0)
        const int a = (m & (1 << b)) ? (m ^ (1 << b)) : 0;
        best = fmaxf(best, g[a]);
      }
      g[m] = v[m] + best;
    }
    __syncthreads();
  }

  // ---- Phase B: FM = min(fm,1), FM[full]=1, FM[empty]=0 (chunk-local) ----
#pragma unroll
  for (int r = 0; r < 4; ++r) {
    const int m = cbase | (r << 6) | lane;
    float val;
    if (m == 0)              val = 0.0f;
    else if (m == NMASK - 1) val = 1.0f;
    else                     val = fminf(g[m], 1.0f);
    g[m] = val;
  }
  // no barrier: writes are chunk-local and Phase C bits 0..7 stay in-chunk

  // ---- Phase C: Moebius transform, g[m] -= g[m ^ bit] ----
  // bits 0..7: both m and m^bit lie inside this wave's 256-mask chunk;
  // wave64 lockstep + in-order LDS => no __syncthreads needed.
#pragma unroll
  for (int b = 0; b < 8; ++b) {
#pragma unroll
    for (int r = 0; r < 2; ++r) {
      const int j = (r << 6) | lane;  // 0..127: masks-with-bit-b index
      const int m =
          cbase | (((j >> b) << (b + 1)) | (1 << b) | (j & ((1 << b) - 1)));
      g[m] -= g[m ^ (1 << b)];
    }
  }
  __syncthreads();
  // bits 8..11 cross chunks: barrier-separated sweeps, 2048 active masks.
#pragma unroll
  for (int b = 8; b < NB; ++b) {
    for (int j = tid; j < 2048; j += 1024) {
      const int m = ((j >> b) << (b + 1)) | (1 << b) | (j & ((1 << b) - 1));
      g[m] -= g[m ^ (1 << b)];
    }
    __syncthreads();
  }

  // ---- batch phase: this block handles batch row blockIdx.x ----
  // Thread t covers masks [4t, 4t+4): mask = (t<<2)|k, so t's bit `bit`
  // is mask bit 2+bit -> feature 2+bit. Low 2 bits handled analytically.
  const float x0l = xs[0], x1l = xs[1], x0u = xs[12], x1u = xs[13];
  float hl = 1.0f, hu = 1.0f;
#pragma unroll
  for (int bit = 0; bit < 10; ++bit) {
    if (tid & (1 << bit)) {
      hl *= xs[2 + bit];
      hu *= xs[14 + bit];
    }
  }
  const float4 w = *reinterpret_cast<const float4*>(&g[tid << 2]);
  const float l3 = x0l * x1l, u3 = x0u * x1u;
  // mask 0 (t=0,k=0) included harmlessly: W[0] == 0.
  float A = hl * (w.x + w.y * x0l + w.z * x1l + w.w * l3);  // fl . W partial
  float B = hu * (w.x + w.y * x0u + w.z * x1u + w.w * u3);  // fu . W partial

  // reduce 1024 threads: wave64 shuffle, then 16-wave LDS combine
#pragma unroll
  for (int off = 32; off > 0; off >>= 1) {
    A += __shfl_down(A, off);
    B += __shfl_down(B, off);
  }
  if (lane == 0) {
    rA[wave] = A;
    rB[wave] = B;
  }
  __syncthreads();
  if (tid == 0) {
    float a = 0.0f, bb = 0.0f;
#pragma unroll
    for (int i = 0; i < 16; ++i) {
      a += rA[i];
      bb += rB[i];
    }
    out[blockIdx.x] = fminf(a, bb);  // left
    out[64 + blockIdx.x] = bb;       // right
  }
}

extern "C" void kernel_launch(void* const* d_in, const int* in_sizes, int n_in,
                              void* d_out, int out_size, void* d_ws,
                              size_t ws_size, hipStream_t stream) {
  const float* x  = (const float*)d_in[0];  // (64, 24) fp32
  const float* ie = (const float*)d_in[1];  // (4094, 1) fp32
  // d_in[2] (fmat) deterministic 0/1 indicator — folded analytically.
  float* out = (float*)d_out;               // 128 floats: left(64), right(64)

  k_fused<<<64, 1024, 0, stream>>>(x, ie, out);
}

// Round 2
// 171.104 us; speedup vs baseline: 1.2288x; 1.0033x over previous
//
#include <hip/hip_runtime.h>

// Problem: N_FEAT=12, BATCH=64.
// Identity (verified in prior session): left = min(fl·W, fu·W), right = fu·W
// where W = Moebius transform (over the 12-bit subset lattice) of
// FM = min(fm, 1), fm the popcount-level DP over |ie_vars|. fmat is a
// deterministic 0/1 subset/parity indicator matrix, folded analytically.
//
// Single fused kernel: 64 blocks (one per batch row), each block rebuilds W
// redundantly in its own LDS (parallel across CUs -> redundancy is free;
// wall time = one block's W-build + trivial batch phase).
//  - ie_vars staged to LDS (coalesced): serial DP chain never touches global.
//  - per-popcount-level compact work lists via colex rank (no atomics).
//  - Phase A reads ONLY the lv actual predecessors per mask (popcount is
//    uniform within a level -> zero divergence; halves LDS reads vs the
//    branchless 12-way form: 24.5k vs 49k ds_read_b32 per block).
//  - Moebius passes for bits 0..7 are wave-chunk-local (lockstep wave64,
//    in-order LDS) -> no barrier; only bits 8..11 need __syncthreads.

#define NB 12
#define NMASK 4096  // 2^12

// C(b, i) for b in 0..11 (rows), i in 0..12 (cols); zero when i > b.
__constant__ int d_BIN[156] = {
    1, 0,  0,  0,   0,   0,   0,   0,   0,  0,  0, 0, 0,   // b=0
    1, 1,  0,  0,   0,   0,   0,   0,   0,  0,  0, 0, 0,   // b=1
    1, 2,  1,  0,   0,   0,   0,   0,   0,  0,  0, 0, 0,   // b=2
    1, 3,  3,  1,   0,   0,   0,   0,   0,  0,  0, 0, 0,   // b=3
    1, 4,  6,  4,   1,   0,   0,   0,   0,  0,  0, 0, 0,   // b=4
    1, 5, 10, 10,   5,   1,   0,   0,   0,  0,  0, 0, 0,   // b=5
    1, 6, 15, 20,  15,   6,   1,   0,   0,  0,  0, 0, 0,   // b=6
    1, 7, 21, 35,  35,  21,   7,   1,   0,  0,  0, 0, 0,   // b=7
    1, 8, 28, 56,  70,  56,  28,   8,   1,  0,  0, 0, 0,   // b=8
    1, 9, 36, 84, 126, 126,  84,  36,   9,  1,  0, 0, 0,   // b=9
    1, 10, 45, 120, 210, 252, 210, 120, 45, 10, 1, 0, 0,   // b=10
    1, 11, 55, 165, 330, 462, 462, 330, 165, 55, 11, 1, 0  // b=11
};

// Level start offsets: OFF[l] = sum_{j=1..l-1} C(12, j)  (mask 0 excluded).
__constant__ int d_OFF[13] = {0, 0, 12, 78, 298, 793, 1585,
                              2509, 3301, 3796, 4016, 4082, 4094};

__global__ __launch_bounds__(1024) void k_fused(
    const float* __restrict__ x, const float* __restrict__ ie,
    float* __restrict__ out) {
  __shared__ float g[NMASK];            // fm -> FM -> W (in place)
  __shared__ float v[NMASK];            // |ie_vars| staged, v[m] = |ie[m-1]|
  __shared__ unsigned short idx[NMASK]; // per-level compact mask lists
  __shared__ float xs[24];              // row of x: [0..11]=datal [12..23]=datau
  __shared__ int sBIN[156];
  __shared__ float rA[16], rB[16];

  const int tid = threadIdx.x;
  const int lane = tid & 63;
  const int wave = tid >> 6;
  const int cbase = wave << 8;  // this wave's exclusive 256-mask chunk

  // Level start offsets (compile-time copy for Phase A's unrolled loop).
  constexpr int OFF_A[13] = {0, 0, 12, 78, 298, 793, 1585,
                             2509, 3301, 3796, 4016, 4082, 4094};

  // ---- stage constants + inputs into LDS (coalesced) ----
  if (tid < 156) sBIN[tid] = d_BIN[tid];
  if (tid < 24) xs[tid] = x[blockIdx.x * 24 + tid];
  for (int i = tid; i < NMASK - 2; i += 1024) v[i + 1] = fabsf(ie[i]);
  __syncthreads();

  // ---- build compact per-popcount-level lists via colex rank ----
  // rank of {b1<...<bl} among popcount-l masks = sum_i C(b_i, i); bijective.
  for (int m = tid; m < NMASK; m += 1024) {
    if (m == 0) {
      g[0] = 0.0f;  // absorbs the single-bit-mask edge case in Phase A
      continue;
    }
    int pc = 0, r = 0;
#pragma unroll
    for (int b = 0; b < NB; ++b)
      if (m & (1 << b)) { ++pc; r += sBIN[b * 13 + pc]; }
    idx[d_OFF[pc] + r] = (unsigned short)m;
  }
  __syncthreads();

  // ---- Phase A: popcount-level DP, fm[m] = v[m] + max_{b in m} fm[m^b] ----
  // Levels 1..11 cover masks 1..4094 (level 12 = {4095} excluded, as in ref).
  // Each level fits one block-sweep (max C(12,6)=924 <= 1024 threads).
  // Popcount is uniform within a level, so the set-bit loop (exactly lv
  // iterations, compile-time constant) has no divergence. For lv==1 the
  // single predecessor is g[0] == 0 -> fm = v (matches the ref's isfinite
  // fallback). For lv>=2 every m^bit >= 1 is a valid predecessor.
#pragma unroll
  for (int lv = 1; lv <= 11; ++lv) {
    const int u = OFF_A[lv] + tid;
    if (u < OFF_A[lv + 1]) {
      const int m = (int)idx[u];
      float best = 0.0f;
      int mm = m;
#pragma unroll
      for (int i = 0; i < lv; ++i) {
        const int b = mm & (-mm);  // lowest set bit
        mm ^= b;
        best = fmaxf(best, g[m ^ b]);
      }
      g[m] = v[m] + best;
    }
    __syncthreads();
  }

  // ---- Phase B: FM = min(fm,1), FM[full]=1, FM[empty]=0 (chunk-local) ----
#pragma unroll
  for (int r = 0; r < 4; ++r) {
    const int m = cbase | (r << 6) | lane;
    float val;
    if (m == 0)              val = 0.0f;
    else if (m == NMASK - 1) val = 1.0f;
    else                     val = fminf(g[m], 1.0f);
    g[m] = val;
  }
  // no barrier: writes are chunk-local and Phase C bits 0..7 stay in-chunk

  // ---- Phase C: Moebius transform, g[m] -= g[m ^ bit] ----
  // bits 0..7: both m and m^bit lie inside this wave's 256-mask chunk;
  // wave64 lockstep + in-order LDS => no __syncthreads needed.
#pragma unroll
  for (int b = 0; b < 8; ++b) {
#pragma unroll
    for (int r = 0; r < 2; ++r) {
      const int j = (r << 6) | lane;  // 0..127: masks-with-bit-b index
      const int m =
          cbase | (((j >> b) << (b + 1)) | (1 << b) | (j & ((1 << b) - 1)));
      g[m] -= g[m ^ (1 << b)];
    }
  }
  __syncthreads();
  // bits 8..11 cross chunks: barrier-separated sweeps, 2048 active masks.
#pragma unroll
  for (int b = 8; b < NB; ++b) {
    for (int j = tid; j < 2048; j += 1024) {
      const int m = ((j >> b) << (b + 1)) | (1 << b) | (j & ((1 << b) - 1));
      g[m] -= g[m ^ (1 << b)];
    }
    __syncthreads();
  }

  // ---- batch phase: this block handles batch row blockIdx.x ----
  // Thread t covers masks [4t, 4t+4): mask = (t<<2)|k, so t's bit `bit`
  // is mask bit 2+bit -> feature 2+bit. Low 2 bits handled analytically.
  float hl = 1.0f, hu = 1.0f;
#pragma unroll
  for (int bit = 0; bit < 10; ++bit) {
    if (tid & (1 << bit)) {
      hl *= xs[2 + bit];
      hu *= xs[14 + bit];
    }
  }
  const float x0l = xs[0], x1l = xs[1], x0u = xs[12], x1u = xs[13];
  const float4 w = *reinterpret_cast<const float4*>(&g[tid << 2]);
  const float l3 = x0l * x1l, u3 = x0u * x1u;
  // mask 0 (t=0,k=0) included harmlessly: W[0] == 0.
  float A = hl * (w.x + w.y * x0l + w.z * x1l + w.w * l3);  // fl . W partial
  float B = hu * (w.x + w.y * x0u + w.z * x1u + w.w * u3);  // fu . W partial

  // reduce 1024 threads: wave64 shuffle, then 16-wave LDS combine
#pragma unroll
  for (int off = 32; off > 0; off >>= 1) {
    A += __shfl_down(A, off);
    B += __shfl_down(B, off);
  }
  if (lane == 0) {
    rA[wave] = A;
    rB[wave] = B;
  }
  __syncthreads();
  if (tid == 0) {
    float a = 0.0f, bb = 0.0f;
#pragma unroll
    for (int i = 0; i < 16; ++i) {
      a += rA[i];
      bb += rB[i];
    }
    out[blockIdx.x] = fminf(a, bb);  // left
    out[64 + blockIdx.x] = bb;       // right
  }
}

extern "C" void kernel_launch(void* const* d_in, const int* in_sizes, int n_in,
                              void* d_out, int out_size, void* d_ws,
                              size_t ws_size, hipStream_t stream) {
  const float* x  = (const float*)d_in[0];  // (64, 24) fp32
  const float* ie = (const float*)d_in[1];  // (4094, 1) fp32
  // d_in[2] (fmat) deterministic 0/1 indicator — folded analytically.
  float* out = (float*)d_out;               // 128 floats: left(64), right(64)

  k_fused<<<64, 1024, 0, stream>>>(x, ie, out);
}